// Round 5
// baseline (344.856 us; speedup 1.0000x reference)
//
#include <hip/hip_runtime.h>
#include <stdint.h>

#define BT 4096
#define DMODEL 2048
#define FDIM 1024
#define NEXP 8
#define NA (BT * 2)
#define MAXT 40                  // 8192/256 + 8 (256-row tiles)
#define NB1 (FDIM / 128)         // 8
#define NB2 (DMODEL / 256)       // 8
#define GRID1 (MAXT * NB1)       // 320
#define GRID2 (MAXT * NB2)       // 320
#define NT1 (DMODEL / 64)        // 32 K-steps
#define NT2 (FDIM / 64)          // 16 K-steps

typedef __attribute__((ext_vector_type(8))) __bf16 bf16x8;
typedef __attribute__((ext_vector_type(4))) float f32x4;

#define FENCE() asm volatile("" ::: "memory")
#define BARRIER() do { FENCE(); __builtin_amdgcn_s_barrier(); FENCE(); } while (0)
#define WAITVM0() asm volatile("s_waitcnt vmcnt(0)" ::: "memory")

__device__ __forceinline__ unsigned short f2bf(float f) {
  union { float f; unsigned int u; } v; v.f = f;
  unsigned int u = v.u;
  unsigned int r = (u + 0x7fffu + ((u >> 16) & 1u)) >> 16;
  return (unsigned short)r;
}
__device__ __forceinline__ float bf2f(unsigned short h) {
  union { unsigned int u; float f; } v; v.u = ((unsigned int)h) << 16;
  return v.f;
}

__device__ __forceinline__ void g2l16(const void* g, void* l) {
  __builtin_amdgcn_global_load_lds((const __attribute__((address_space(1))) void*)g,
                                   (__attribute__((address_space(3))) void*)l, 16, 0, 0);
}

// ---------------- router (+ x -> bf16 conversion fused, float4 loads) ----------------

__global__ void k_router(const float* __restrict__ x, const float* __restrict__ rw,
                         unsigned short* __restrict__ xbf,
                         int* __restrict__ tok_e, float* __restrict__ tok_w) {
  int wid = threadIdx.x >> 6;
  int lane = threadIdx.x & 63;
  int t = blockIdx.x * 4 + wid;
  float acc[8];
#pragma unroll
  for (int e = 0; e < 8; e++) acc[e] = 0.0f;
  const float* xr = x + (size_t)t * DMODEL;
  unsigned short* xbr = xbf + (size_t)t * DMODEL;
#pragma unroll
  for (int d0 = lane * 4; d0 < DMODEL; d0 += 256) {
    float4 xv = *(const float4*)(xr + d0);
    ushort4 o = make_ushort4(f2bf(xv.x), f2bf(xv.y), f2bf(xv.z), f2bf(xv.w));
    *(ushort4*)(xbr + d0) = o;
    const float* xs = &xv.x;
#pragma unroll
    for (int j = 0; j < 4; j++) {
      const float4* r4 = (const float4*)(rw + (size_t)(d0 + j) * NEXP);
      float4 ra = r4[0], rb = r4[1];
      float xj = xs[j];
      acc[0] += xj * ra.x; acc[1] += xj * ra.y; acc[2] += xj * ra.z; acc[3] += xj * ra.w;
      acc[4] += xj * rb.x; acc[5] += xj * rb.y; acc[6] += xj * rb.z; acc[7] += xj * rb.w;
    }
  }
#pragma unroll
  for (int e = 0; e < 8; e++) {
    float v = acc[e];
#pragma unroll
    for (int off = 32; off > 0; off >>= 1) v += __shfl_xor(v, off);
    acc[e] = v;
  }
  if (lane == 0) {
    int e0 = 0; float s0 = acc[0];
#pragma unroll
    for (int e = 1; e < 8; e++) if (acc[e] > s0) { s0 = acc[e]; e0 = e; }
    int e1 = (e0 == 0) ? 1 : 0; float s1 = acc[e1];
#pragma unroll
    for (int e = 0; e < 8; e++) if (e != e0 && acc[e] > s1) { s1 = acc[e]; e1 = e; }
    float w0 = 1.0f / (1.0f + __expf(s1 - s0));
    tok_e[t * 2] = e0; tok_e[t * 2 + 1] = e1;
    tok_w[t * 2] = w0; tok_w[t * 2 + 1] = 1.0f - w0;
  }
}

// histogram + scan + 256-row tile table + zero cursors
__global__ void k_scanbuild(const int* __restrict__ tok_e, int* __restrict__ offsets,
                            int* __restrict__ tile_e, int* __restrict__ tile_y,
                            int* __restrict__ ntiles, int* __restrict__ cursors) {
  __shared__ int hist[NEXP];
  int tid = threadIdx.x;
  if (tid < NEXP) hist[tid] = 0;
  __syncthreads();
  for (int i = tid; i < NA; i += 256) atomicAdd(&hist[tok_e[i]], 1);
  __syncthreads();
  if (tid == 0) {
    int s = 0;
    for (int e = 0; e < NEXP; e++) { offsets[e] = s; s += hist[e]; }
    offsets[NEXP] = s;
    int idx = 0;
    for (int e = 0; e < NEXP; e++) {
      int nt = (hist[e] + 255) >> 8;
      for (int y = 0; y < nt; y++) { tile_e[idx] = e; tile_y[idx] = y; idx++; }
    }
    *ntiles = idx;
    for (int i = idx; i < MAXT; i++) { tile_e[i] = 0; tile_y[i] = 0; }
  }
  if (tid < NEXP) cursors[tid] = 0;
}

__global__ void k_scatter(const int* __restrict__ tok_e, const float* __restrict__ tok_w,
                          const int* __restrict__ offsets, int* __restrict__ cursors,
                          int* __restrict__ assign_token, float* __restrict__ assign_w,
                          int* __restrict__ tok2pos) {
  int i = blockIdx.x * 256 + threadIdx.x;
  if (i >= NA) return;
  int e = tok_e[i];
  int pos = offsets[e] + atomicAdd(&cursors[e], 1);
  assign_token[pos] = i >> 1;
  assign_w[pos] = tok_w[i];
  tok2pos[i] = pos;
}

// all three weight transposes: src [E][K][N] f32 -> dst [E][N][K] bf16
__global__ void k_transpose_all(const float* __restrict__ gw, const float* __restrict__ uw,
                                const float* __restrict__ dw,
                                unsigned short* __restrict__ wtg, unsigned short* __restrict__ wtu,
                                unsigned short* __restrict__ wtd) {
  __shared__ float tile[64][65];
  int z = blockIdx.y;
  const float* src; unsigned short* dst; int N;
  if (z < 8)       { src = gw + (size_t)z * DMODEL * FDIM;        dst = wtg + (size_t)z * DMODEL * FDIM;        N = FDIM; }
  else if (z < 16) { src = uw + (size_t)(z - 8) * DMODEL * FDIM;  dst = wtu + (size_t)(z - 8) * DMODEL * FDIM;  N = FDIM; }
  else             { src = dw + (size_t)(z - 16) * FDIM * DMODEL; dst = wtd + (size_t)(z - 16) * FDIM * DMODEL; N = DMODEL; }
  int ntx = N >> 6;
  int bx = blockIdx.x;
  int n0 = (bx % ntx) * 64, k0 = (bx / ntx) * 64;
  int rr = threadIdx.x >> 4, cc = threadIdx.x & 15;
#pragma unroll
  for (int i = 0; i < 4; i++) {
    int k = rr + i * 16;
    float4 v = *(const float4*)(src + (size_t)(k0 + k) * N + n0 + cc * 4);
    tile[k][cc * 4 + 0] = v.x; tile[k][cc * 4 + 1] = v.y;
    tile[k][cc * 4 + 2] = v.z; tile[k][cc * 4 + 3] = v.w;
  }
  __syncthreads();
  int K = (z < 16) ? DMODEL : FDIM;
#pragma unroll
  for (int i = 0; i < 4; i++) {
    int n = rr + i * 16;
    ushort4 o = make_ushort4(f2bf(tile[cc * 4 + 0][n]), f2bf(tile[cc * 4 + 1][n]),
                             f2bf(tile[cc * 4 + 2][n]), f2bf(tile[cc * 4 + 3][n]));
    *(ushort4*)(dst + (size_t)(n0 + n) * K + k0 + cc * 4) = o;
  }
}

// ---------------- GEMM1: act = silu(Xg @ Wg) * (Xg @ Wu) ----------------
// BM=256 BN=128 BK=64, 512 thr (8 waves 2Mx4N), dbuf LDS 128KB, 4-phase K-step,
// prefetch issued phases 0-1, single vmcnt(0) at K-step end. T2 swizzle.

__global__ __launch_bounds__(512, 2) void k_gemm1(
    const unsigned short* __restrict__ xbf,
    const unsigned short* __restrict__ wtg,
    const unsigned short* __restrict__ wtu,
    const int* __restrict__ offsets,
    const int* __restrict__ tile_e, const int* __restrict__ tile_y,
    const int* __restrict__ ntiles,
    const int* __restrict__ assign_token,
    unsigned short* __restrict__ act) {
  const int flat = blockIdx.x;
  const int wgid = (flat & 7) * (GRID1 / 8) + (flat >> 3);
  const int ti = wgid % MAXT;          // ti-fastest: each XCD owns one n-block
  const int nb = wgid / MAXT;
  if (ti >= *ntiles) return;
  const int e = tile_e[ti];
  const int row_beg = offsets[e], row_end = offsets[e + 1];
  const int m_base = row_beg + tile_y[ti] * 256;
  const int n_base = nb * 128;

  __shared__ unsigned short As[2][256][64];
  __shared__ unsigned short Bg[2][128][64];
  __shared__ unsigned short Bu[2][128][64];

  const int tid = threadIdx.x;
  const int lane = tid & 63, wid = tid >> 6;
  const int wm = wid >> 2, wn = wid & 3;
  const int l15 = lane & 15;
  const int srow = tid >> 3;                         // 0..63
  const int scol_d = (tid & 7) * 8;
  const int scol_s = ((tid & 7) ^ (srow & 7)) * 8;   // pre-swizzled global col
  const int sw = (lane & 7) * 8;                     // read-side XOR

  const unsigned short* wg_e = wtg + (size_t)e * FDIM * DMODEL + (size_t)n_base * DMODEL;
  const unsigned short* wu_e = wtu + (size_t)e * FDIM * DMODEL + (size_t)n_base * DMODEL;

  size_t arow[4];
#pragma unroll
  for (int i = 0; i < 4; i++) {
    int slot = m_base + i * 64 + srow;
    if (slot >= row_end) slot = row_end - 1;
    arow[i] = (size_t)assign_token[slot] * DMODEL;
  }

  f32x4 accg[8][2], accu[8][2];
#pragma unroll
  for (int m = 0; m < 8; m++)
#pragma unroll
    for (int n = 0; n < 2; n++) {
      accg[m][n] = f32x4{0.f, 0.f, 0.f, 0.f};
      accu[m][n] = f32x4{0.f, 0.f, 0.f, 0.f};
    }

  auto stageA = [&](int buf, int k0) {
#pragma unroll
    for (int i = 0; i < 4; i++)
      g2l16(xbf + arow[i] + k0 + scol_s, &As[buf][i * 64 + srow][scol_d]);
  };
  auto stageB = [&](int buf, int k0) {
#pragma unroll
    for (int i = 0; i < 2; i++)
      g2l16(wg_e + (size_t)(i * 64 + srow) * DMODEL + k0 + scol_s, &Bg[buf][i * 64 + srow][scol_d]);
#pragma unroll
    for (int i = 0; i < 2; i++)
      g2l16(wu_e + (size_t)(i * 64 + srow) * DMODEL + k0 + scol_s, &Bu[buf][i * 64 + srow][scol_d]);
  };

  stageA(0, 0); stageB(0, 0);
  WAITVM0(); BARRIER();

  for (int t = 0; t < NT1; ++t) {
    const int cur = t & 1, nxt = cur ^ 1;
    const int k1 = (t + 1) * 64;
    const bool pref = (t + 1 < NT1);

#pragma unroll
    for (int kk = 0; kk < 2; kk++) {
      const int ko = kk * 32 + (lane >> 4) * 8;
      bf16x8 a[8];
#pragma unroll
      for (int m = 0; m < 8; m++)
        a[m] = *(const bf16x8*)&As[cur][wm * 128 + m * 16 + l15][ko ^ sw];
      bf16x8 b0 = *(const bf16x8*)&Bg[cur][wn * 32 + l15][ko ^ sw];
      bf16x8 b1 = *(const bf16x8*)&Bg[cur][wn * 32 + 16 + l15][ko ^ sw];
      if (pref && kk == 0) stageA(nxt, k1);
      BARRIER();
      __builtin_amdgcn_s_setprio(1);
#pragma unroll
      for (int m = 0; m < 8; m++) {
        accg[m][0] = __builtin_amdgcn_mfma_f32_16x16x32_bf16(a[m], b0, accg[m][0], 0, 0, 0);
        accg[m][1] = __builtin_amdgcn_mfma_f32_16x16x32_bf16(a[m], b1, accg[m][1], 0, 0, 0);
      }
      __builtin_amdgcn_s_setprio(0);
      BARRIER();
      b0 = *(const bf16x8*)&Bu[cur][wn * 32 + l15][ko ^ sw];
      b1 = *(const bf16x8*)&Bu[cur][wn * 32 + 16 + l15][ko ^ sw];
      if (pref && kk == 0) stageB(nxt, k1);
      BARRIER();
      __builtin_amdgcn_s_setprio(1);
#pragma unroll
      for (int m = 0; m < 8; m++) {
        accu[m][0] = __builtin_amdgcn_mfma_f32_16x16x32_bf16(a[m], b0, accu[m][0], 0, 0, 0);
        accu[m][1] = __builtin_amdgcn_mfma_f32_16x16x32_bf16(a[m], b1, accu[m][1], 0, 0, 0);
      }
      __builtin_amdgcn_s_setprio(0);
      if (kk == 1 && pref) WAITVM0();
      BARRIER();
    }
  }

  const int cr = (lane >> 4) * 4;
#pragma unroll
  for (int m = 0; m < 8; m++) {
#pragma unroll
    for (int j = 0; j < 4; j++) {
      int slot = m_base + wm * 128 + m * 16 + cr + j;
      if (slot < row_end) {
        unsigned short* dst = act + (size_t)slot * FDIM + n_base + wn * 32 + l15;
#pragma unroll
        for (int n = 0; n < 2; n++) {
          float g = accg[m][n][j], u = accu[m][n][j];
          float h = (g / (1.0f + __expf(-g))) * u;
          dst[n * 16] = f2bf(h);
        }
      }
    }
  }
}

// ---------------- GEMM2: out_pa = (act @ Wd) * w ----------------
// BM=256 BN=256 BK=64, same 4-phase schedule (split by kk x n-half).

__global__ __launch_bounds__(512, 2) void k_gemm2(
    const unsigned short* __restrict__ act,
    const unsigned short* __restrict__ wtd,
    const int* __restrict__ offsets,
    const int* __restrict__ tile_e, const int* __restrict__ tile_y,
    const int* __restrict__ ntiles,
    const float* __restrict__ assign_w,
    unsigned short* __restrict__ out_pa) {
  const int flat = blockIdx.x;
  const int wgid = (flat & 7) * (GRID2 / 8) + (flat >> 3);
  const int ti = wgid % MAXT;
  const int nb = wgid / MAXT;
  if (ti >= *ntiles) return;
  const int e = tile_e[ti];
  const int row_beg = offsets[e], row_end = offsets[e + 1];
  const int m_base = row_beg + tile_y[ti] * 256;
  const int n_base = nb * 256;

  __shared__ unsigned short As[2][256][64];
  __shared__ unsigned short Bs[2][256][64];

  const int tid = threadIdx.x;
  const int lane = tid & 63, wid = tid >> 6;
  const int wm = wid >> 2, wn = wid & 3;
  const int l15 = lane & 15;
  const int srow = tid >> 3;
  const int scol_d = (tid & 7) * 8;
  const int scol_s = ((tid & 7) ^ (srow & 7)) * 8;
  const int sw = (lane & 7) * 8;

  const unsigned short* wd_e = wtd + (size_t)e * DMODEL * FDIM + (size_t)n_base * FDIM;

  size_t arow[4];
#pragma unroll
  for (int i = 0; i < 4; i++) {
    int slot = m_base + i * 64 + srow;
    if (slot >= row_end) slot = row_end - 1;
    arow[i] = (size_t)slot * FDIM;
  }

  f32x4 acc[8][4];
#pragma unroll
  for (int m = 0; m < 8; m++)
#pragma unroll
    for (int n = 0; n < 4; n++) acc[m][n] = f32x4{0.f, 0.f, 0.f, 0.f};

  auto stageA = [&](int buf, int k0) {
#pragma unroll
    for (int i = 0; i < 4; i++)
      g2l16(act + arow[i] + k0 + scol_s, &As[buf][i * 64 + srow][scol_d]);
  };
  auto stageB = [&](int buf, int k0) {
#pragma unroll
    for (int i = 0; i < 4; i++)
      g2l16(wd_e + (size_t)(i * 64 + srow) * FDIM + k0 + scol_s, &Bs[buf][i * 64 + srow][scol_d]);
  };

  stageA(0, 0); stageB(0, 0);
  WAITVM0(); BARRIER();

  for (int t = 0; t < NT2; ++t) {
    const int cur = t & 1, nxt = cur ^ 1;
    const int k1 = (t + 1) * 64;
    const bool pref = (t + 1 < NT2);

#pragma unroll
    for (int kk = 0; kk < 2; kk++) {
      const int ko = kk * 32 + (lane >> 4) * 8;
      bf16x8 a[8];
#pragma unroll
      for (int m = 0; m < 8; m++)
        a[m] = *(const bf16x8*)&As[cur][wm * 128 + m * 16 + l15][ko ^ sw];
      bf16x8 b0 = *(const bf16x8*)&Bs[cur][wn * 64 + l15][ko ^ sw];
      bf16x8 b1 = *(const bf16x8*)&Bs[cur][wn * 64 + 16 + l15][ko ^ sw];
      if (pref && kk == 0) stageA(nxt, k1);
      BARRIER();
      __builtin_amdgcn_s_setprio(1);
#pragma unroll
      for (int m = 0; m < 8; m++) {
        acc[m][0] = __builtin_amdgcn_mfma_f32_16x16x32_bf16(a[m], b0, acc[m][0], 0, 0, 0);
        acc[m][1] = __builtin_amdgcn_mfma_f32_16x16x32_bf16(a[m], b1, acc[m][1], 0, 0, 0);
      }
      __builtin_amdgcn_s_setprio(0);
      BARRIER();
      b0 = *(const bf16x8*)&Bs[cur][wn * 64 + 32 + l15][ko ^ sw];
      b1 = *(const bf16x8*)&Bs[cur][wn * 64 + 48 + l15][ko ^ sw];
      if (pref && kk == 0) stageB(nxt, k1);
      BARRIER();
      __builtin_amdgcn_s_setprio(1);
#pragma unroll
      for (int m = 0; m < 8; m++) {
        acc[m][2] = __builtin_amdgcn_mfma_f32_16x16x32_bf16(a[m], b0, acc[m][2], 0, 0, 0);
        acc[m][3] = __builtin_amdgcn_mfma_f32_16x16x32_bf16(a[m], b1, acc[m][3], 0, 0, 0);
      }
      __builtin_amdgcn_s_setprio(0);
      if (kk == 1 && pref) WAITVM0();
      BARRIER();
    }
  }

  const int cr = (lane >> 4) * 4;
#pragma unroll
  for (int m = 0; m < 8; m++) {
#pragma unroll
    for (int j = 0; j < 4; j++) {
      int slot = m_base + wm * 128 + m * 16 + cr + j;
      if (slot < row_end) {
        float w = assign_w[slot];
        unsigned short* dst = out_pa + (size_t)slot * DMODEL + n_base + wn * 64 + l15;
#pragma unroll
        for (int n = 0; n < 4; n++)
          dst[n * 16] = f2bf(acc[m][n][j] * w);
      }
    }
  }
}

__global__ void k_combine(const unsigned short* __restrict__ out_pa,
                          const int* __restrict__ tok2pos,
                          float* __restrict__ out) {
  int t = blockIdx.x;
  int p0 = tok2pos[t * 2], p1 = tok2pos[t * 2 + 1];
  int c = threadIdx.x;
  const ushort4* a = (const ushort4*)(out_pa + (size_t)p0 * DMODEL + c * 8);
  const ushort4* b = (const ushort4*)(out_pa + (size_t)p1 * DMODEL + c * 8);
  ushort4 a0 = a[0], a1 = a[1], b0 = b[0], b1 = b[1];
  float* o = out + (size_t)t * DMODEL + c * 8;
  o[0] = bf2f(a0.x) + bf2f(b0.x);
  o[1] = bf2f(a0.y) + bf2f(b0.y);
  o[2] = bf2f(a0.z) + bf2f(b0.z);
  o[3] = bf2f(a0.w) + bf2f(b0.w);
  o[4] = bf2f(a1.x) + bf2f(b1.x);
  o[5] = bf2f(a1.y) + bf2f(b1.y);
  o[6] = bf2f(a1.z) + bf2f(b1.z);
  o[7] = bf2f(a1.w) + bf2f(b1.w);
}

// ---------------- host ----------------

extern "C" void kernel_launch(void* const* d_in, const int* in_sizes, int n_in,
                              void* d_out, int out_size, void* d_ws, size_t ws_size,
                              hipStream_t stream) {
  const float* x  = (const float*)d_in[0];
  const float* rw = (const float*)d_in[1];
  const float* gw = (const float*)d_in[2];
  const float* uw = (const float*)d_in[3];
  const float* dw = (const float*)d_in[4];
  float* out = (float*)d_out;

  char* ws = (char*)d_ws;
  size_t off = 0;
  auto alloc = [&](size_t bytes) {
    size_t o = off;
    off += (bytes + 255) & ~(size_t)255;
    return o;
  };
  unsigned short* xbf    = (unsigned short*)(ws + alloc((size_t)BT * DMODEL * 2));
  unsigned short* wtg    = (unsigned short*)(ws + alloc((size_t)NEXP * FDIM * DMODEL * 2));
  unsigned short* wtu    = (unsigned short*)(ws + alloc((size_t)NEXP * FDIM * DMODEL * 2));
  unsigned short* wtd    = (unsigned short*)(ws + alloc((size_t)NEXP * DMODEL * FDIM * 2));
  unsigned short* act    = (unsigned short*)(ws + alloc((size_t)NA * FDIM * 2));
  unsigned short* out_pa = (unsigned short*)(ws + alloc((size_t)NA * DMODEL * 2));
  int*   offsets = (int*)(ws + alloc((NEXP + 1) * 4));
  int*   cursors = (int*)(ws + alloc(NEXP * 4));
  int*   tok_e   = (int*)(ws + alloc(NA * 4));
  float* tok_w   = (float*)(ws + alloc(NA * 4));
  int*   assign_token = (int*)(ws + alloc(NA * 4));
  float* assign_w     = (float*)(ws + alloc(NA * 4));
  int*   tok2pos      = (int*)(ws + alloc(NA * 4));
  int*   tile_e       = (int*)(ws + alloc(MAXT * 4));
  int*   tile_y       = (int*)(ws + alloc(MAXT * 4));
  int*   ntiles       = (int*)(ws + alloc(4));
  if (off > ws_size) return;  // workspace too small -> fail loudly (poison stays)

  k_router<<<BT / 4, 256, 0, stream>>>(x, rw, xbf, tok_e, tok_w);
  k_scanbuild<<<1, 256, 0, stream>>>(tok_e, offsets, tile_e, tile_y, ntiles, cursors);
  k_scatter<<<NA / 256, 256, 0, stream>>>(tok_e, tok_w, offsets, cursors,
                                          assign_token, assign_w, tok2pos);
  k_transpose_all<<<dim3(512, 24), 256, 0, stream>>>(gw, uw, dw, wtg, wtu, wtd);
  k_gemm1<<<GRID1, 512, 0, stream>>>(xbf, wtg, wtu, offsets,
                                     tile_e, tile_y, ntiles, assign_token, act);
  k_gemm2<<<GRID2, 512, 0, stream>>>(act, wtd, offsets,
                                     tile_e, tile_y, ntiles, assign_w, out_pa);
  k_combine<<<BT, 256, 0, stream>>>(out_pa, tok2pos, out);
}

// Round 6
// 301.005 us; speedup vs baseline: 1.1457x; 1.1457x over previous
//
#include <hip/hip_runtime.h>
#include <stdint.h>

#define BT 4096
#define DMODEL 2048
#define FDIM 1024
#define NEXP 8
#define NA (BT * 2)
#define MAXTILES 72   // 8192/128 + 8 (128-row tiles)

typedef __attribute__((ext_vector_type(8))) __bf16 bf16x8;
typedef __attribute__((ext_vector_type(4))) float f32x4;

__device__ __forceinline__ unsigned short f2bf(float f) {
  union { float f; unsigned int u; } v; v.f = f;
  unsigned int u = v.u;
  unsigned int r = (u + 0x7fffu + ((u >> 16) & 1u)) >> 16;
  return (unsigned short)r;
}
__device__ __forceinline__ float bf2f(unsigned short h) {
  union { unsigned int u; float f; } v; v.u = ((unsigned int)h) << 16;
  return v.f;
}

__device__ __forceinline__ void g2l16(const void* g, void* l) {
  __builtin_amdgcn_global_load_lds((const __attribute__((address_space(1))) void*)g,
                                   (__attribute__((address_space(3))) void*)l, 16, 0, 0);
}

// ---------------- router (+ x -> bf16 conversion fused, float4 loads) ----------------

__global__ void k_router(const float* __restrict__ x, const float* __restrict__ rw,
                         unsigned short* __restrict__ xbf,
                         int* __restrict__ tok_e, float* __restrict__ tok_w) {
  int wid = threadIdx.x >> 6;
  int lane = threadIdx.x & 63;
  int t = blockIdx.x * 4 + wid;
  float acc[8];
#pragma unroll
  for (int e = 0; e < 8; e++) acc[e] = 0.0f;
  const float* xr = x + (size_t)t * DMODEL;
  unsigned short* xbr = xbf + (size_t)t * DMODEL;
#pragma unroll
  for (int d0 = lane * 4; d0 < DMODEL; d0 += 256) {
    float4 xv = *(const float4*)(xr + d0);
    ushort4 o = make_ushort4(f2bf(xv.x), f2bf(xv.y), f2bf(xv.z), f2bf(xv.w));
    *(ushort4*)(xbr + d0) = o;
    const float* xs = &xv.x;
#pragma unroll
    for (int j = 0; j < 4; j++) {
      const float4* r4 = (const float4*)(rw + (size_t)(d0 + j) * NEXP);
      float4 ra = r4[0], rb = r4[1];
      float xj = xs[j];
      acc[0] += xj * ra.x; acc[1] += xj * ra.y; acc[2] += xj * ra.z; acc[3] += xj * ra.w;
      acc[4] += xj * rb.x; acc[5] += xj * rb.y; acc[6] += xj * rb.z; acc[7] += xj * rb.w;
    }
  }
#pragma unroll
  for (int e = 0; e < 8; e++) {
    float v = acc[e];
#pragma unroll
    for (int off = 32; off > 0; off >>= 1) v += __shfl_xor(v, off);
    acc[e] = v;
  }
  if (lane == 0) {
    int e0 = 0; float s0 = acc[0];
#pragma unroll
    for (int e = 1; e < 8; e++) if (acc[e] > s0) { s0 = acc[e]; e0 = e; }
    int e1 = (e0 == 0) ? 1 : 0; float s1 = acc[e1];
#pragma unroll
    for (int e = 0; e < 8; e++) if (e != e0 && acc[e] > s1) { s1 = acc[e]; e1 = e; }
    float w0 = 1.0f / (1.0f + __expf(s1 - s0));
    tok_e[t * 2] = e0; tok_e[t * 2 + 1] = e1;
    tok_w[t * 2] = w0; tok_w[t * 2 + 1] = 1.0f - w0;
  }
}

// histogram + scan + 128-row tile table + zero cursors
__global__ void k_scanbuild(const int* __restrict__ tok_e, int* __restrict__ offsets,
                            int* __restrict__ tile_e, int* __restrict__ tile_y,
                            int* __restrict__ ntiles, int* __restrict__ cursors) {
  __shared__ int hist[NEXP];
  int tid = threadIdx.x;
  if (tid < NEXP) hist[tid] = 0;
  __syncthreads();
  for (int i = tid; i < NA; i += 256) atomicAdd(&hist[tok_e[i]], 1);
  __syncthreads();
  if (tid == 0) {
    int s = 0;
    for (int e = 0; e < NEXP; e++) { offsets[e] = s; s += hist[e]; }
    offsets[NEXP] = s;
    int idx = 0;
    for (int e = 0; e < NEXP; e++) {
      int nt = (hist[e] + 127) >> 7;
      for (int y = 0; y < nt; y++) { tile_e[idx] = e; tile_y[idx] = y; idx++; }
    }
    *ntiles = idx;
    for (int i = idx; i < MAXTILES; i++) { tile_e[i] = 0; tile_y[i] = 0; }
  }
  if (tid < NEXP) cursors[tid] = 0;
}

__global__ void k_scatter(const int* __restrict__ tok_e, const float* __restrict__ tok_w,
                          const int* __restrict__ offsets, int* __restrict__ cursors,
                          int* __restrict__ assign_token, float* __restrict__ assign_w,
                          int* __restrict__ tok2pos) {
  int i = blockIdx.x * 256 + threadIdx.x;
  if (i >= NA) return;
  int e = tok_e[i];
  int pos = offsets[e] + atomicAdd(&cursors[e], 1);
  assign_token[pos] = i >> 1;
  assign_w[pos] = tok_w[i];
  tok2pos[i] = pos;
}

// weight transpose+convert+pack, one launch.
// z in 0..7: gate -> wtgu rows (f>>5)*64 + (f&31)        [E][2048][2048]
// z in 8..15: up  -> wtgu rows (f>>5)*64 + 32 + (f&31)
// z in 16..23: down -> wtd [E][DMODEL][FDIM], row = n
__global__ void k_transpose_all(const float* __restrict__ gw, const float* __restrict__ uw,
                                const float* __restrict__ dw,
                                unsigned short* __restrict__ wtgu,
                                unsigned short* __restrict__ wtd) {
  __shared__ float tile[64][65];
  int z = blockIdx.y;
  const float* src; unsigned short* dst; int N, K, Kd;
  if (z < 8)       { src = gw + (size_t)z * DMODEL * FDIM;        dst = wtgu + (size_t)z * 2 * FDIM * DMODEL;        N = FDIM;   K = DMODEL; Kd = DMODEL; }
  else if (z < 16) { src = uw + (size_t)(z - 8) * DMODEL * FDIM;  dst = wtgu + (size_t)(z - 8) * 2 * FDIM * DMODEL;  N = FDIM;   K = DMODEL; Kd = DMODEL; }
  else             { src = dw + (size_t)(z - 16) * FDIM * DMODEL; dst = wtd + (size_t)(z - 16) * FDIM * DMODEL;      N = DMODEL; K = FDIM;   Kd = FDIM; }
  int ntx = N >> 6;
  int bx = blockIdx.x;
  int n0 = (bx % ntx) * 64, k0 = (bx / ntx) * 64;
  int rr = threadIdx.x >> 4, cc = threadIdx.x & 15;
#pragma unroll
  for (int i = 0; i < 4; i++) {
    int k = rr + i * 16;
    float4 v = *(const float4*)(src + (size_t)(k0 + k) * N + n0 + cc * 4);
    tile[k][cc * 4 + 0] = v.x; tile[k][cc * 4 + 1] = v.y;
    tile[k][cc * 4 + 2] = v.z; tile[k][cc * 4 + 3] = v.w;
  }
  __syncthreads();
#pragma unroll
  for (int i = 0; i < 4; i++) {
    int n = rr + i * 16;
    int gr = n0 + n;
    int orow;
    if (z < 8)       orow = ((gr & ~31) << 1) + (gr & 31);        // gate
    else if (z < 16) orow = ((gr & ~31) << 1) + 32 + (gr & 31);   // up
    else             orow = gr;                                    // down
    ushort4 o = make_ushort4(f2bf(tile[cc * 4 + 0][n]), f2bf(tile[cc * 4 + 1][n]),
                             f2bf(tile[cc * 4 + 2][n]), f2bf(tile[cc * 4 + 3][n]));
    *(ushort4*)(dst + (size_t)orow * Kd + k0 + cc * 4) = o;
  }
}

// ---------------- GEMM1: pure GEMM over packed wtgu (N=2048), SiLU in-register ----------------
// 128x128 tile, 256 thr (2x2 waves, 64x64 per wave), BK=64, m97 2-barrier loop,
// T2 swizzle (pre-swizzled global col + XOR read). 4 blocks/CU.

__global__ __launch_bounds__(256, 4) void k_gemm1(
    const unsigned short* __restrict__ xbf,
    const unsigned short* __restrict__ wtgu,
    const int* __restrict__ offsets,
    const int* __restrict__ tile_e, const int* __restrict__ tile_y,
    const int* __restrict__ ntiles,
    const int* __restrict__ assign_token,
    unsigned short* __restrict__ act) {
  const int ti = blockIdx.y;
  if (ti >= *ntiles) return;
  const int e = tile_e[ti];
  const int row_beg = offsets[e], row_end = offsets[e + 1];
  const int m_base = row_beg + tile_y[ti] * 128;
  const int n_base = blockIdx.x * 128;   // in packed 2048-row space

  __shared__ unsigned short As[128][64];
  __shared__ unsigned short Bs[128][64];

  const int tid = threadIdx.x;
  const int lane = tid & 63, wid = tid >> 6;
  const int wr = wid >> 1, wc = wid & 1;
  const int srow = wid * 8 + (lane >> 3);
  const int scol_d = (lane & 7) * 8;
  const int scol_s = ((lane & 7) ^ (lane >> 3)) * 8;
  const int sw = (lane & 7) * 8;

  const unsigned short* wb = wtgu + (size_t)e * 2 * FDIM * DMODEL + (size_t)n_base * DMODEL;

  size_t arow[4];
#pragma unroll
  for (int i = 0; i < 4; i++) {
    int slot = m_base + i * 32 + srow;
    if (slot >= row_end) slot = row_end - 1;
    arow[i] = (size_t)assign_token[slot] * DMODEL;
  }

  f32x4 acc[4][4];
#pragma unroll
  for (int m = 0; m < 4; m++)
#pragma unroll
    for (int n = 0; n < 4; n++) acc[m][n] = f32x4{0.f, 0.f, 0.f, 0.f};

  for (int k0 = 0; k0 < DMODEL; k0 += 64) {
    __syncthreads();
#pragma unroll
    for (int i = 0; i < 4; i++)
      g2l16(xbf + arow[i] + k0 + scol_s, &As[i * 32 + srow][scol_d]);
#pragma unroll
    for (int i = 0; i < 4; i++)
      g2l16(wb + (size_t)(i * 32 + srow) * DMODEL + k0 + scol_s, &Bs[i * 32 + srow][scol_d]);
    __syncthreads();

#pragma unroll
    for (int kk = 0; kk < 2; kk++) {
      const int ko = kk * 32 + (lane >> 4) * 8;
      bf16x8 a[4], b[4];
#pragma unroll
      for (int m = 0; m < 4; m++)
        a[m] = *(const bf16x8*)&As[wr * 64 + m * 16 + (lane & 15)][ko ^ sw];
#pragma unroll
      for (int n = 0; n < 4; n++)
        b[n] = *(const bf16x8*)&Bs[wc * 64 + n * 16 + (lane & 15)][ko ^ sw];
#pragma unroll
      for (int m = 0; m < 4; m++)
#pragma unroll
        for (int n = 0; n < 4; n++)
          acc[m][n] = __builtin_amdgcn_mfma_f32_16x16x32_bf16(a[m], b[n], acc[m][n], 0, 0, 0);
    }
  }

  // packed cols: n-frag 0,1 = gate, 2,3 = up (same f range). f = (n_base>>1) + wc*32 + n*16 + col
  const int cr = (lane >> 4) * 4;
  const int ccc = lane & 15;
#pragma unroll
  for (int m = 0; m < 4; m++) {
#pragma unroll
    for (int j = 0; j < 4; j++) {
      int slot = m_base + wr * 64 + m * 16 + cr + j;
      if (slot < row_end) {
        unsigned short* dst = act + (size_t)slot * FDIM + (n_base >> 1) + wc * 32 + ccc;
#pragma unroll
        for (int n = 0; n < 2; n++) {
          float g = acc[m][n][j], u = acc[m][n + 2][j];
          float h = (g / (1.0f + __expf(-g))) * u;
          dst[n * 16] = f2bf(h);
        }
      }
    }
  }
}

// ---------------- GEMM2: out_pa = (act @ Wd) * w ----------------

__global__ __launch_bounds__(256, 4) void k_gemm2(
    const unsigned short* __restrict__ act,
    const unsigned short* __restrict__ wtd,
    const int* __restrict__ offsets,
    const int* __restrict__ tile_e, const int* __restrict__ tile_y,
    const int* __restrict__ ntiles,
    const float* __restrict__ assign_w,
    unsigned short* __restrict__ out_pa) {
  const int ti = blockIdx.y;
  if (ti >= *ntiles) return;
  const int e = tile_e[ti];
  const int row_beg = offsets[e], row_end = offsets[e + 1];
  const int m_base = row_beg + tile_y[ti] * 128;
  const int n_base = blockIdx.x * 128;

  __shared__ unsigned short As[128][64];
  __shared__ unsigned short Bs[128][64];

  const int tid = threadIdx.x;
  const int lane = tid & 63, wid = tid >> 6;
  const int wr = wid >> 1, wc = wid & 1;
  const int srow = wid * 8 + (lane >> 3);
  const int scol_d = (lane & 7) * 8;
  const int scol_s = ((lane & 7) ^ (lane >> 3)) * 8;
  const int sw = (lane & 7) * 8;

  const unsigned short* wd_e = wtd + (size_t)e * DMODEL * FDIM + (size_t)n_base * FDIM;

  size_t arow[4];
#pragma unroll
  for (int i = 0; i < 4; i++) {
    int slot = m_base + i * 32 + srow;
    if (slot >= row_end) slot = row_end - 1;
    arow[i] = (size_t)slot * FDIM;
  }

  f32x4 acc[4][4];
#pragma unroll
  for (int m = 0; m < 4; m++)
#pragma unroll
    for (int n = 0; n < 4; n++) acc[m][n] = f32x4{0.f, 0.f, 0.f, 0.f};

  for (int k0 = 0; k0 < FDIM; k0 += 64) {
    __syncthreads();
#pragma unroll
    for (int i = 0; i < 4; i++)
      g2l16(act + arow[i] + k0 + scol_s, &As[i * 32 + srow][scol_d]);
#pragma unroll
    for (int i = 0; i < 4; i++)
      g2l16(wd_e + (size_t)(i * 32 + srow) * FDIM + k0 + scol_s, &Bs[i * 32 + srow][scol_d]);
    __syncthreads();

#pragma unroll
    for (int kk = 0; kk < 2; kk++) {
      const int ko = kk * 32 + (lane >> 4) * 8;
      bf16x8 a[4], b[4];
#pragma unroll
      for (int m = 0; m < 4; m++)
        a[m] = *(const bf16x8*)&As[wr * 64 + m * 16 + (lane & 15)][ko ^ sw];
#pragma unroll
      for (int n = 0; n < 4; n++)
        b[n] = *(const bf16x8*)&Bs[wc * 64 + n * 16 + (lane & 15)][ko ^ sw];
#pragma unroll
      for (int m = 0; m < 4; m++)
#pragma unroll
        for (int n = 0; n < 4; n++)
          acc[m][n] = __builtin_amdgcn_mfma_f32_16x16x32_bf16(a[m], b[n], acc[m][n], 0, 0, 0);
    }
  }

  const int cr = (lane >> 4) * 4;
  const int ccc = lane & 15;
#pragma unroll
  for (int m = 0; m < 4; m++) {
#pragma unroll
    for (int j = 0; j < 4; j++) {
      int slot = m_base + wr * 64 + m * 16 + cr + j;
      if (slot < row_end) {
        float w = assign_w[slot];
        unsigned short* dst = out_pa + (size_t)slot * DMODEL + n_base + wc * 64 + ccc;
#pragma unroll
        for (int n = 0; n < 4; n++)
          dst[n * 16] = f2bf(acc[m][n][j] * w);
      }
    }
  }
}

__global__ void k_combine(const unsigned short* __restrict__ out_pa,
                          const int* __restrict__ tok2pos,
                          float* __restrict__ out) {
  int t = blockIdx.x;
  int p0 = tok2pos[t * 2], p1 = tok2pos[t * 2 + 1];
  int c = threadIdx.x;
  const ushort4* a = (const ushort4*)(out_pa + (size_t)p0 * DMODEL + c * 8);
  const ushort4* b = (const ushort4*)(out_pa + (size_t)p1 * DMODEL + c * 8);
  ushort4 a0 = a[0], a1 = a[1], b0 = b[0], b1 = b[1];
  float* o = out + (size_t)t * DMODEL + c * 8;
  o[0] = bf2f(a0.x) + bf2f(b0.x);
  o[1] = bf2f(a0.y) + bf2f(b0.y);
  o[2] = bf2f(a0.z) + bf2f(b0.z);
  o[3] = bf2f(a0.w) + bf2f(b0.w);
  o[4] = bf2f(a1.x) + bf2f(b1.x);
  o[5] = bf2f(a1.y) + bf2f(b1.y);
  o[6] = bf2f(a1.z) + bf2f(b1.z);
  o[7] = bf2f(a1.w) + bf2f(b1.w);
}

// ---------------- host ----------------

extern "C" void kernel_launch(void* const* d_in, const int* in_sizes, int n_in,
                              void* d_out, int out_size, void* d_ws, size_t ws_size,
                              hipStream_t stream) {
  const float* x  = (const float*)d_in[0];
  const float* rw = (const float*)d_in[1];
  const float* gw = (const float*)d_in[2];
  const float* uw = (const float*)d_in[3];
  const float* dw = (const float*)d_in[4];
  float* out = (float*)d_out;

  char* ws = (char*)d_ws;
  size_t off = 0;
  auto alloc = [&](size_t bytes) {
    size_t o = off;
    off += (bytes + 255) & ~(size_t)255;
    return o;
  };
  unsigned short* xbf    = (unsigned short*)(ws + alloc((size_t)BT * DMODEL * 2));
  unsigned short* wtgu   = (unsigned short*)(ws + alloc((size_t)NEXP * 2 * FDIM * DMODEL * 2));
  unsigned short* wtd    = (unsigned short*)(ws + alloc((size_t)NEXP * DMODEL * FDIM * 2));
  unsigned short* act    = (unsigned short*)(ws + alloc((size_t)NA * FDIM * 2));
  unsigned short* out_pa = (unsigned short*)(ws + alloc((size_t)NA * DMODEL * 2));
  int*   offsets = (int*)(ws + alloc((NEXP + 1) * 4));
  int*   cursors = (int*)(ws + alloc(NEXP * 4));
  int*   tok_e   = (int*)(ws + alloc(NA * 4));
  float* tok_w   = (float*)(ws + alloc(NA * 4));
  int*   assign_token = (int*)(ws + alloc(NA * 4));
  float* assign_w     = (float*)(ws + alloc(NA * 4));
  int*   tok2pos      = (int*)(ws + alloc(NA * 4));
  int*   tile_e       = (int*)(ws + alloc(MAXTILES * 4));
  int*   tile_y       = (int*)(ws + alloc(MAXTILES * 4));
  int*   ntiles       = (int*)(ws + alloc(4));
  if (off > ws_size) return;  // workspace too small -> fail loudly (poison stays)

  k_router<<<BT / 4, 256, 0, stream>>>(x, rw, xbf, tok_e, tok_w);
  k_scanbuild<<<1, 256, 0, stream>>>(tok_e, offsets, tile_e, tile_y, ntiles, cursors);
  k_scatter<<<NA / 256, 256, 0, stream>>>(tok_e, tok_w, offsets, cursors,
                                          assign_token, assign_w, tok2pos);
  k_transpose_all<<<dim3(512, 24), 256, 0, stream>>>(gw, uw, dw, wtgu, wtd);
  k_gemm1<<<dim3(DMODEL * 2 / 128 / 2, MAXTILES), 256, 0, stream>>>(xbf, wtgu, offsets,
                                                                    tile_e, tile_y, ntiles,
                                                                    assign_token, act);
  k_gemm2<<<dim3(DMODEL / 128, MAXTILES), 256, 0, stream>>>(act, wtd, offsets,
                                                            tile_e, tile_y, ntiles,
                                                            assign_w, out_pa);
  k_combine<<<BT, 256, 0, stream>>>(out_pa, tok2pos, out);
}